// Round 7
// baseline (740.704 us; speedup 1.0000x reference)
//
#include <hip/hip_runtime.h>
#include <math.h>

// Problem constants (from reference)
#define Nn 50000
#define Ee 500000
#define Cc 256
#define Hh 128
#define Ll 4
#define Gg 64
#define Kk 8
#define NCc 2

#define NB 196  // ceil(Nn/256)
#define GY 391  // ceil(Nn/128)

typedef __attribute__((ext_vector_type(8))) short short8;
typedef __attribute__((ext_vector_type(4))) float f32x4;

__device__ __forceinline__ unsigned short f2bf(float f) {
    union { float f; unsigned int u; } v;
    v.f = f;
    unsigned int u = v.u;
    return (unsigned short)((u + 0x7FFFu + ((u >> 16) & 1u)) >> 16);
}
__device__ __forceinline__ float bf2f(unsigned short s) {
    union { float f; unsigned int u; } v;
    v.u = ((unsigned int)s) << 16;
    return v.f;
}

// direct global->LDS, 16 B per lane; lds dest = wave-uniform base + lane*16
__device__ __forceinline__ void gll16(const void* g, void* l) {
    __builtin_amdgcn_global_load_lds((const __attribute__((address_space(1))) void*)g,
                                     (__attribute__((address_space(3))) void*)l, 16, 0, 0);
}

// ---------------- CSR build ----------------

__global__ void hist_kernel(const int* __restrict__ dst, int* __restrict__ deg) {
    int e = blockIdx.x * 256 + threadIdx.x;
    if (e < Ee) atomicAdd(&deg[dst[e]], 1);
}

__global__ __launch_bounds__(256) void bsum_kernel(const int* __restrict__ deg,
                                                   int* __restrict__ bsum) {
    __shared__ int ws[4];
    int t = threadIdx.x;
    int i = blockIdx.x * 256 + t;
    int v = (i < Nn) ? deg[i] : 0;
#pragma unroll
    for (int o = 32; o; o >>= 1) v += __shfl_down(v, o, 64);
    if ((t & 63) == 0) ws[t >> 6] = v;
    __syncthreads();
    if (t == 0) bsum[blockIdx.x] = ws[0] + ws[1] + ws[2] + ws[3];
}

__global__ __launch_bounds__(256) void bscan_kernel(const int* __restrict__ bsum,
                                                    int* __restrict__ boff,
                                                    int* __restrict__ off) {
    __shared__ int sc[256];
    int t = threadIdx.x;
    int v = (t < NB) ? bsum[t] : 0;
    sc[t] = v;
    __syncthreads();
    for (int o = 1; o < 256; o <<= 1) {
        int u = (t >= o) ? sc[t - o] : 0;
        __syncthreads();
        sc[t] += u;
        __syncthreads();
    }
    if (t < NB) boff[t] = sc[t] - v;  // exclusive
    if (t == NB - 1) off[Nn] = sc[t];
}

__global__ __launch_bounds__(256) void offsets_kernel(const int* __restrict__ deg,
                                                      const int* __restrict__ boff,
                                                      int* __restrict__ off,
                                                      int* __restrict__ pos) {
    __shared__ int sc[256];
    int t = threadIdx.x;
    int i = blockIdx.x * 256 + t;
    int v = (i < Nn) ? deg[i] : 0;
    sc[t] = v;
    __syncthreads();
    for (int o = 1; o < 256; o <<= 1) {
        int u = (t >= o) ? sc[t - o] : 0;
        __syncthreads();
        sc[t] += u;
        __syncthreads();
    }
    int excl = sc[t] - v + boff[blockIdx.x];
    if (i < Nn) {
        off[i] = excl;
        pos[i] = excl;
    }
}

__global__ void scatter_kernel(const int* __restrict__ src, const int* __restrict__ dst,
                               const float* __restrict__ attr, int* __restrict__ pos,
                               int2* __restrict__ sedge) {
    int e = blockIdx.x * 256 + threadIdx.x;
    if (e < Ee) {
        int d = dst[e];
        int p = atomicAdd(&pos[d], 1);
        sedge[p] = make_int2(src[e], __float_as_int(attr[e]));
    }
}

// ---------------- weight convert + transpose to bf16 [N][K] ----------------
// wt layout: [0, 65536)       proj  [256 n][256 k]  (n<128: lin_src col, else lin_dst)
//            [65536, 196608)  w1[l] [256 n][128 k]
//            [196608, 327680) w2[l] [128 n][256 k]

__global__ void wconv_kernel(const float* __restrict__ lin_src_w,
                             const float* __restrict__ lin_dst_w,
                             const float* __restrict__ mlp_w1,
                             const float* __restrict__ mlp_w2,
                             unsigned short* __restrict__ wt) {
    int idx = blockIdx.x * 256 + threadIdx.x;
    if (idx >= 327680) return;
    float val;
    if (idx < 65536) {
        int n = idx >> 8, k = idx & 255;
        val = (n < 128) ? lin_src_w[k * 128 + n] : lin_dst_w[k * 128 + (n - 128)];
    } else if (idx < 196608) {
        int r = idx - 65536;
        int l = r >> 15, e = r & 32767;
        int n = e >> 7, k = e & 127;
        val = mlp_w1[(size_t)l * 32768 + k * 256 + n];
    } else {
        int r = idx - 196608;
        int l = r >> 15, e = r & 32767;
        int n = e >> 8, k = e & 255;
        val = mlp_w2[(size_t)l * 32768 + k * 128 + n];
    }
    wt[idx] = f2bf(val);
}

// ---------------- x -> bf16 (once) ----------------

__global__ void xconv_kernel(const float* __restrict__ x, unsigned short* __restrict__ xbf) {
    int i = blockIdx.x * 256 + threadIdx.x;  // octet index, total Nn*Cc/8 = 1.6M
    if (i < Nn * Cc / 8) {
        const float4* p = (const float4*)(x + (size_t)i * 8);
        float4 a = p[0], b = p[1];
        unsigned short t[8];
        t[0] = f2bf(a.x); t[1] = f2bf(a.y); t[2] = f2bf(a.z); t[3] = f2bf(a.w);
        t[4] = f2bf(b.x); t[5] = f2bf(b.y); t[6] = f2bf(b.z); t[7] = f2bf(b.w);
        *(short8*)(xbf + (size_t)i * 8) = *(short8*)t;
    }
}

// ---------------- bf16 MFMA GEMM, 128x64, BK=64, double-buffered LDS ----------------
// C[M,N] = A[M,K](bf16) @ Bt[N][K](bf16).
// Prefetch tile k+1 via global_load_lds into the idle buffer AFTER the barrier, so the
// loads fly during tile k's ds_read+MFMA phase; end-of-iter barrier drain is pre-paid.
// mode 0: OutB = bf16(v)                         (proj; bias2 covers cols >= 128)
// mode 1: OutB = bf16(relu(bn(v)))               (w1 + mlp-BN)
// mode 2: h = v;            HB = bf16(h); OutB = bf16(relu(norm(h)))  (w2, layer 0)
// mode 3: h = bf2f(HB) + v; HB = bf16(h); OutB = bf16(relu(norm(h)))  (w2, mid layers)
// mode 4: h = bf2f(HB) + v;               OutB = bf16(relu(norm(h)))  (w2, last layer)

#define BM 128
#define BN 64
#define BK 64

__global__ __launch_bounds__(256) void gemm_kernel(
    const unsigned short* __restrict__ A, const unsigned short* __restrict__ Bt,
    const float* __restrict__ bias, const float* __restrict__ bias2,
    const float* __restrict__ g_, const float* __restrict__ b_,
    const float* __restrict__ m_, const float* __restrict__ v_,
    unsigned short* __restrict__ HB, unsigned short* __restrict__ OutB,
    int M, int N, int K, int mode) {
    __shared__ __align__(16) unsigned short As[2][BM * BK];  // 2 x 16 KB
    __shared__ __align__(16) unsigned short Bs[2][BN * BK];  // 2 x 8 KB
    int tid = threadIdx.x;
    int m0 = blockIdx.y * BM, n0 = blockIdx.x * BN;
    int wave = tid >> 6, lane = tid & 63;
    int wr = wave >> 1, wc = wave & 1;  // 2x2 wave grid: 64 rows x 32 cols per wave
    int lrow = lane & 15, quad = lane >> 4;

    f32x4 acc[4][2];
#pragma unroll
    for (int i = 0; i < 4; i++)
#pragma unroll
        for (int j = 0; j < 2; j++) acc[i][j] = (f32x4){0.f, 0.f, 0.f, 0.f};

    auto stage = [&](int k0, int b) {
        // A: 128 rows x 64 k = 1024 units of 16 lanes * 16 B; 4 gll16/thread
#pragma unroll
        for (int j = 0; j < 4; j++) {
            int fi = j * 256 + tid;
            int u = fi >> 4, l = fi & 15;
            int tile = u >> 3, kb = u & 7;
            int gr = min(m0 + tile * 16 + l, M - 1);  // clamp: OOB rows unused in epilogue
            gll16(A + (size_t)gr * K + k0 + kb * 8, &As[b][(fi & ~63) * 8]);
        }
        // B: 64 n-rows x 64 k; 2 gll16/thread
#pragma unroll
        for (int j = 0; j < 2; j++) {
            int fi = j * 256 + tid;
            int u = fi >> 4, l = fi & 15;
            int tile = u >> 3, kb = u & 7;
            gll16(Bt + (size_t)(n0 + tile * 16 + l) * K + k0 + kb * 8, &Bs[b][(fi & ~63) * 8]);
        }
    };

    stage(0, 0);
    __syncthreads();
    int cur = 0;
    for (int k0 = 0; k0 < K; k0 += BK) {
        if (k0 + BK < K) stage(k0 + BK, cur ^ 1);  // prefetch overlaps compute below
#pragma unroll
        for (int s = 0; s < 2; s++) {
            short8 af[4], bf[2];
#pragma unroll
            for (int mt = 0; mt < 4; mt++)
                af[mt] =
                    *(const short8*)&As[cur][(((wr * 4 + mt) * 8 + s * 4 + quad) * 16 + lrow) * 8];
#pragma unroll
            for (int nt = 0; nt < 2; nt++)
                bf[nt] =
                    *(const short8*)&Bs[cur][(((wc * 2 + nt) * 8 + s * 4 + quad) * 16 + lrow) * 8];
#pragma unroll
            for (int mt = 0; mt < 4; mt++)
#pragma unroll
                for (int nt = 0; nt < 2; nt++)
                    acc[mt][nt] = __builtin_amdgcn_mfma_f32_16x16x32_bf16(af[mt], bf[nt],
                                                                         acc[mt][nt], 0, 0, 0);
        }
        __syncthreads();  // drains prefetch (overlapped) + ds_reads; then swap
        cur ^= 1;
    }

    // ---- epilogue ----
#pragma unroll
    for (int nt = 0; nt < 2; nt++) {
        int gc = n0 + wc * 32 + nt * 16 + lrow;
        float bs = bias2 ? ((gc < 128) ? bias[gc] : bias2[gc - 128]) : bias[gc];
        float g = 0.f, bb = 0.f, mm = 0.f, inv = 0.f;
        if (mode >= 1) {
            g = g_[gc];
            bb = b_[gc];
            mm = m_[gc];
            inv = rsqrtf(v_[gc] + 1e-5f);
        }
#pragma unroll
        for (int mt = 0; mt < 4; mt++) {
#pragma unroll
            for (int r = 0; r < 4; r++) {
                int gr = m0 + wr * 64 + mt * 16 + quad * 4 + r;
                if (gr < M) {
                    float v = acc[mt][nt][r] + bs;
                    size_t idx = (size_t)gr * N + gc;
                    if (mode == 0) {
                        OutB[idx] = f2bf(v);
                    } else if (mode == 1) {
                        OutB[idx] = f2bf(fmaxf(g * (v - mm) * inv + bb, 0.f));
                    } else {
                        float h = v + ((mode >= 3) ? bf2f(HB[idx]) : 0.f);
                        if (mode <= 3) HB[idx] = f2bf(h);
                        OutB[idx] = f2bf(fmaxf(g * (h - mm) * inv + bb, 0.f));
                    }
                }
            }
        }
    }
}

// ---------------- Fused GENConv aggregation ----------------
// One dst node per 128-thread block (round-5 measured-good shape). Softmax is
// shift-invariant and z = msg*t is bounded (msg = relu+eps ~ O(1), t ~ 0.1), so no
// max-tracking is needed: 1 exp/edge, mathematically identical.

__global__ __launch_bounds__(128) void agg_kernel(
    const unsigned short* __restrict__ xs, int xss,
    const unsigned short* __restrict__ xd, int xds,
    const int2* __restrict__ sedge, const int* __restrict__ off,
    const float* __restrict__ ew, const float* __restrict__ eb,
    const float* __restrict__ tptr, unsigned short* __restrict__ outb) {
    int d = blockIdx.x;
    int hh = threadIdx.x;
    int s0 = off[d], s1 = off[d + 1];
    float w = ew[hh], b = eb[hh];
    float tl = tptr[0];
    float denom = 0.f, num = 0.f;

#define EDGE_STEP(xv, av)                                        \
    {                                                            \
        float msg = fmaxf((xv) + fmaf((av), w, b), 0.f) + 1e-7f; \
        float e = __expf(msg * tl);                              \
        denom += e;                                              \
        num = fmaf(msg, e, num);                                 \
    }

    int j = s0;
    for (; j + 3 < s1; j += 4) {
        int2 e0 = sedge[j], e1 = sedge[j + 1], e2 = sedge[j + 2], e3 = sedge[j + 3];
        float x0 = bf2f(xs[(size_t)e0.x * xss + hh]);
        float x1 = bf2f(xs[(size_t)e1.x * xss + hh]);
        float x2 = bf2f(xs[(size_t)e2.x * xss + hh]);
        float x3 = bf2f(xs[(size_t)e3.x * xss + hh]);
        EDGE_STEP(x0, __int_as_float(e0.y))
        EDGE_STEP(x1, __int_as_float(e1.y))
        EDGE_STEP(x2, __int_as_float(e2.y))
        EDGE_STEP(x3, __int_as_float(e3.y))
    }
    for (; j < s1; j++) {
        int2 e = sedge[j];
        float xv = bf2f(xs[(size_t)e.x * xss + hh]);
        EDGE_STEP(xv, __int_as_float(e.y))
    }
    float agg = num / fmaxf(denom, 1e-16f);  // empty segment -> 0, matches ref
    outb[(size_t)d * Hh + hh] = f2bf(agg + bf2f(xd[(size_t)d * xds + hh]));
#undef EDGE_STEP
}

// ---------------- mean-pool over pre-normed bf16 ----------------

#define PCHUNK 100

__global__ __launch_bounds__(128) void pool_kernel(
    const unsigned short* __restrict__ hb, const int* __restrict__ batch,
    float* __restrict__ pooled, float* __restrict__ cnt) {
    int hh = threadIdx.x;
    int i0 = blockIdx.x * PCHUNK;
    int i1 = min(i0 + PCHUNK, Nn);
    if (i0 >= Nn) return;
    int cur = batch[i0];
    float sum = 0.f, c = 0.f;
    for (int i = i0; i < i1; i++) {
        int gid = batch[i];
        float val = bf2f(hb[(size_t)i * Hh + hh]);
        if (gid != cur) {
            atomicAdd(&pooled[(size_t)cur * Hh + hh], sum);
            if (hh == 0) atomicAdd(&cnt[cur], c);
            cur = gid;
            sum = 0.f;
            c = 0.f;
        }
        sum += val;
        c += 1.f;
    }
    atomicAdd(&pooled[(size_t)cur * Hh + hh], sum);
    if (hh == 0) atomicAdd(&cnt[cur], c);
}

// ---------------- classifier ----------------

__global__ __launch_bounds__(128) void cls_kernel(const float* __restrict__ pooled,
                                                  const float* __restrict__ cnt,
                                                  const float* __restrict__ clinical,
                                                  const float* __restrict__ w,
                                                  const float* __restrict__ bias,
                                                  float* __restrict__ out) {
    int t = threadIdx.x;
    int g = t >> 1, c = t & 1;
    float inv = 1.f / fmaxf(cnt[g], 1.f);
    float s = bias[c];
    for (int j = 0; j < Hh; j++) s += pooled[g * Hh + j] * inv * w[j * NCc + c];
    for (int k = 0; k < Kk; k++) s += clinical[g * Kk + k] * w[(Hh + k) * NCc + c];
    out[g * NCc + c] = s;
}

// ---------------- launch ----------------

extern "C" void kernel_launch(void* const* d_in, const int* in_sizes, int n_in,
                              void* d_out, int out_size, void* d_ws, size_t ws_size,
                              hipStream_t stream) {
    const float* x = (const float*)d_in[0];
    const int* eidx = (const int*)d_in[1];
    const float* eattr = (const float*)d_in[2];
    const int* batch = (const int*)d_in[3];
    const float* clinical = (const float*)d_in[4];
    const float* lin_src_b = (const float*)d_in[6];
    const float* lin_dst_b = (const float*)d_in[8];
    const float* edge_w = (const float*)d_in[9];
    const float* edge_b = (const float*)d_in[10];
    const float* tt = (const float*)d_in[11];
    const float* mlp_b1 = (const float*)d_in[13];
    const float* bn_g = (const float*)d_in[14];
    const float* bn_b = (const float*)d_in[15];
    const float* bn_m = (const float*)d_in[16];
    const float* bn_v = (const float*)d_in[17];
    const float* mlp_b2 = (const float*)d_in[19];
    const float* norm_g = (const float*)d_in[20];
    const float* norm_b = (const float*)d_in[21];
    const float* norm_m = (const float*)d_in[22];
    const float* norm_v = (const float*)d_in[23];
    const float* cls_w = (const float*)d_in[24];
    const float* cls_b = (const float*)d_in[25];
    float* out = (float*)d_out;

    const int* src = eidx;
    const int* dst = eidx + Ee;

    char* ws = (char*)d_ws;
    size_t off_b = 0;
    auto alloc = [&](size_t bytes) -> void* {
        void* p = ws + off_b;
        off_b += (bytes + 255) & ~(size_t)255;
        return p;
    };
    unsigned short* xbf = (unsigned short*)alloc((size_t)Nn * Cc * 2);
    unsigned short* xsd = (unsigned short*)alloc((size_t)Nn * 256 * 2);
    unsigned short* rbuf = (unsigned short*)alloc((size_t)Nn * Hh * 2);
    unsigned short* aggout = (unsigned short*)alloc((size_t)Nn * Hh * 2);
    unsigned short* hmid = (unsigned short*)alloc((size_t)Nn * 2 * Hh * 2);
    unsigned short* pnorm = (unsigned short*)alloc((size_t)Nn * Hh * 2);
    unsigned short* hbuf = (unsigned short*)alloc((size_t)Nn * Hh * 2);
    int* deg = (int*)alloc((Nn + 1) * 4);
    int* offp = (int*)alloc((Nn + 1) * 4);
    int* pos = (int*)alloc((size_t)Nn * 4);
    int* bsum = (int*)alloc(NB * 4);
    int* boff = (int*)alloc(NB * 4);
    int2* sedge = (int2*)alloc((size_t)Ee * 8);
    float* pooled = (float*)alloc((size_t)Gg * Hh * 4);
    float* cntb = (float*)alloc(Gg * 4);
    unsigned short* wt = (unsigned short*)alloc((size_t)327680 * 2);

    hipMemsetAsync(deg, 0, (Nn + 1) * 4, stream);
    hipMemsetAsync(pooled, 0, (size_t)Gg * Hh * 4, stream);
    hipMemsetAsync(cntb, 0, Gg * 4, stream);

    hist_kernel<<<(Ee + 255) / 256, 256, 0, stream>>>(dst, deg);
    bsum_kernel<<<NB, 256, 0, stream>>>(deg, bsum);
    bscan_kernel<<<1, 256, 0, stream>>>(bsum, boff, offp);
    offsets_kernel<<<NB, 256, 0, stream>>>(deg, boff, offp, pos);
    scatter_kernel<<<(Ee + 255) / 256, 256, 0, stream>>>(src, dst, eattr, pos, sedge);
    wconv_kernel<<<1280, 256, 0, stream>>>((const float*)d_in[5], (const float*)d_in[7],
                                           (const float*)d_in[12], (const float*)d_in[18], wt);
    xconv_kernel<<<6250, 256, 0, stream>>>(x, xbf);

    const unsigned short* wt_proj = wt;
    const unsigned short* wt_w1 = wt + 65536;
    const unsigned short* wt_w2 = wt + 196608;

    // Fused projection: xsd[:, :128] = x@Wsrc+b, xsd[:, 128:] = x@Wdst+b
    gemm_kernel<<<dim3(4, GY), 256, 0, stream>>>(xbf, wt_proj, lin_src_b, lin_dst_b, nullptr,
                                                 nullptr, nullptr, nullptr, nullptr, xsd, Nn,
                                                 256, Cc, 0);

    for (int l = 0; l < Ll; l++) {
        const unsigned short* cxs;
        const unsigned short* cxd;
        int xss, xds;
        if (l == 0) {
            cxs = xsd;
            xss = 256;
            cxd = xsd + 128;
            xds = 256;
        } else {
            cxs = rbuf;
            xss = Hh;
            cxd = rbuf;
            xds = Hh;
        }
        agg_kernel<<<Nn, 128, 0, stream>>>(cxs, xss, cxd, xds, sedge, offp, edge_w + l * Hh,
                                           edge_b + l * Hh, tt + l, aggout);
        // w1: [N,128] @ [128,256] -> hmid (mlp-BN + ReLU, bf16)
        gemm_kernel<<<dim3(4, GY), 256, 0, stream>>>(
            aggout, wt_w1 + (size_t)l * 32768, mlp_b1 + l * 2 * Hh, nullptr,
            bn_g + l * 2 * Hh, bn_b + l * 2 * Hh, bn_m + l * 2 * Hh, bn_v + l * 2 * Hh,
            nullptr, hmid, Nn, 2 * Hh, Hh, 1);
        // w2: [N,256] @ [256,128]; fused residual + next-layer (or final) norm
        int nl = (l == Ll - 1) ? 0 : (l + 1);
        int mode = (l == 0) ? 2 : ((l == Ll - 1) ? 4 : 3);
        unsigned short* outB = (l == Ll - 1) ? pnorm : rbuf;
        gemm_kernel<<<dim3(2, GY), 256, 0, stream>>>(
            hmid, wt_w2 + (size_t)l * 32768, mlp_b2 + l * Hh, nullptr,
            norm_g + nl * Hh, norm_b + nl * Hh, norm_m + nl * Hh, norm_v + nl * Hh,
            hbuf, outB, Nn, Hh, 2 * Hh, mode);
    }

    pool_kernel<<<(Nn + PCHUNK - 1) / PCHUNK, 128, 0, stream>>>(pnorm, batch, pooled, cntb);
    cls_kernel<<<1, 128, 0, stream>>>(pooled, cntb, clinical, cls_w, cls_b, out);
}

// Round 8
// 711.337 us; speedup vs baseline: 1.0413x; 1.0413x over previous
//
#include <hip/hip_runtime.h>
#include <math.h>

// Problem constants (from reference)
#define Nn 50000
#define Ee 500000
#define Cc 256
#define Hh 128
#define Ll 4
#define Gg 64
#define Kk 8
#define NCc 2

#define NB 196  // ceil(Nn/256)
#define GY 391  // ceil(Nn/128)

typedef __attribute__((ext_vector_type(8))) short short8;
typedef __attribute__((ext_vector_type(4))) float f32x4;

__device__ __forceinline__ unsigned short f2bf(float f) {
    union { float f; unsigned int u; } v;
    v.f = f;
    unsigned int u = v.u;
    return (unsigned short)((u + 0x7FFFu + ((u >> 16) & 1u)) >> 16);
}
__device__ __forceinline__ float bf2f(unsigned short s) {
    union { float f; unsigned int u; } v;
    v.u = ((unsigned int)s) << 16;
    return v.f;
}

// direct global->LDS, 16 B per lane; lds dest = wave-uniform base + lane*16
__device__ __forceinline__ void gll16(const void* g, void* l) {
    __builtin_amdgcn_global_load_lds((const __attribute__((address_space(1))) void*)g,
                                     (__attribute__((address_space(3))) void*)l, 16, 0, 0);
}

// ---------------- CSR build ----------------

__global__ void hist_kernel(const int* __restrict__ dst, int* __restrict__ deg) {
    int e = blockIdx.x * 256 + threadIdx.x;
    if (e < Ee) atomicAdd(&deg[dst[e]], 1);
}

__global__ __launch_bounds__(256) void bsum_kernel(const int* __restrict__ deg,
                                                   int* __restrict__ bsum) {
    __shared__ int ws[4];
    int t = threadIdx.x;
    int i = blockIdx.x * 256 + t;
    int v = (i < Nn) ? deg[i] : 0;
#pragma unroll
    for (int o = 32; o; o >>= 1) v += __shfl_down(v, o, 64);
    if ((t & 63) == 0) ws[t >> 6] = v;
    __syncthreads();
    if (t == 0) bsum[blockIdx.x] = ws[0] + ws[1] + ws[2] + ws[3];
}

__global__ __launch_bounds__(256) void bscan_kernel(const int* __restrict__ bsum,
                                                    int* __restrict__ boff,
                                                    int* __restrict__ off) {
    __shared__ int sc[256];
    int t = threadIdx.x;
    int v = (t < NB) ? bsum[t] : 0;
    sc[t] = v;
    __syncthreads();
    for (int o = 1; o < 256; o <<= 1) {
        int u = (t >= o) ? sc[t - o] : 0;
        __syncthreads();
        sc[t] += u;
        __syncthreads();
    }
    if (t < NB) boff[t] = sc[t] - v;  // exclusive
    if (t == NB - 1) off[Nn] = sc[t];
}

__global__ __launch_bounds__(256) void offsets_kernel(const int* __restrict__ deg,
                                                      const int* __restrict__ boff,
                                                      int* __restrict__ off,
                                                      int* __restrict__ pos) {
    __shared__ int sc[256];
    int t = threadIdx.x;
    int i = blockIdx.x * 256 + t;
    int v = (i < Nn) ? deg[i] : 0;
    sc[t] = v;
    __syncthreads();
    for (int o = 1; o < 256; o <<= 1) {
        int u = (t >= o) ? sc[t - o] : 0;
        __syncthreads();
        sc[t] += u;
        __syncthreads();
    }
    int excl = sc[t] - v + boff[blockIdx.x];
    if (i < Nn) {
        off[i] = excl;
        pos[i] = excl;
    }
}

__global__ void scatter_kernel(const int* __restrict__ src, const int* __restrict__ dst,
                               const float* __restrict__ attr, int* __restrict__ pos,
                               int2* __restrict__ sedge) {
    int e = blockIdx.x * 256 + threadIdx.x;
    if (e < Ee) {
        int d = dst[e];
        int p = atomicAdd(&pos[d], 1);
        sedge[p] = make_int2(src[e], __float_as_int(attr[e]));
    }
}

// ---------------- weight convert + transpose to bf16 [N][K] ----------------
// wt layout: [0, 65536)       proj  [256 n][256 k]  (n<128: lin_src col, else lin_dst)
//            [65536, 196608)  w1[l] [256 n][128 k]
//            [196608, 327680) w2[l] [128 n][256 k]

__global__ void wconv_kernel(const float* __restrict__ lin_src_w,
                             const float* __restrict__ lin_dst_w,
                             const float* __restrict__ mlp_w1,
                             const float* __restrict__ mlp_w2,
                             unsigned short* __restrict__ wt) {
    int idx = blockIdx.x * 256 + threadIdx.x;
    if (idx >= 327680) return;
    float val;
    if (idx < 65536) {
        int n = idx >> 8, k = idx & 255;
        val = (n < 128) ? lin_src_w[k * 128 + n] : lin_dst_w[k * 128 + (n - 128)];
    } else if (idx < 196608) {
        int r = idx - 65536;
        int l = r >> 15, e = r & 32767;
        int n = e >> 7, k = e & 127;
        val = mlp_w1[(size_t)l * 32768 + k * 256 + n];
    } else {
        int r = idx - 196608;
        int l = r >> 15, e = r & 32767;
        int n = e >> 8, k = e & 255;
        val = mlp_w2[(size_t)l * 32768 + k * 128 + n];
    }
    wt[idx] = f2bf(val);
}

// ---------------- x -> bf16 (once) ----------------

__global__ void xconv_kernel(const float* __restrict__ x, unsigned short* __restrict__ xbf) {
    int i = blockIdx.x * 256 + threadIdx.x;  // octet index, total Nn*Cc/8 = 1.6M
    if (i < Nn * Cc / 8) {
        const float4* p = (const float4*)(x + (size_t)i * 8);
        float4 a = p[0], b = p[1];
        unsigned short t[8];
        t[0] = f2bf(a.x); t[1] = f2bf(a.y); t[2] = f2bf(a.z); t[3] = f2bf(a.w);
        t[4] = f2bf(b.x); t[5] = f2bf(b.y); t[6] = f2bf(b.z); t[7] = f2bf(b.w);
        *(short8*)(xbf + (size_t)i * 8) = *(short8*)t;
    }
}

// ---------------- bf16 MFMA GEMM, 128x64, BK=128, single-buffer gll staging ----------------
// C[M,N] = A[M,K](bf16) @ Bt[N][K](bf16).  K % 128 == 0 (K = 128 or 256 here).
// BK=128 -> w1 (K=128) runs with ONE barrier pair per block; K=256 with two.
// LDS fragment-order unit16 (tile, kb): shorts [(tile*16+kb)*128 ...]; staging dest is
// wave-uniform base + lane*16 (global_load_lds contract); fragment ds_read_b128 contiguous.
// mode 0: OutB = bf16(v)                         (proj; bias2 covers cols >= 128)
// mode 1: OutB = bf16(relu(bn(v)))               (w1 + mlp-BN)
// mode 2: h = v;            HB = bf16(h); OutB = bf16(relu(norm(h)))  (w2, layer 0)
// mode 3: h = bf2f(HB) + v; HB = bf16(h); OutB = bf16(relu(norm(h)))  (w2, mid layers)
// mode 4: h = bf2f(HB) + v;               OutB = bf16(relu(norm(h)))  (w2, last layer)

#define BM 128
#define BN 64
#define BK 128

__global__ __launch_bounds__(256) void gemm_kernel(
    const unsigned short* __restrict__ A, const unsigned short* __restrict__ Bt,
    const float* __restrict__ bias, const float* __restrict__ bias2,
    const float* __restrict__ g_, const float* __restrict__ b_,
    const float* __restrict__ m_, const float* __restrict__ v_,
    unsigned short* __restrict__ HB, unsigned short* __restrict__ OutB,
    int M, int N, int K, int mode) {
    __shared__ __align__(16) unsigned short As[BM * BK];  // 32 KB
    __shared__ __align__(16) unsigned short Bs[BN * BK];  // 16 KB
    int tid = threadIdx.x;
    int m0 = blockIdx.y * BM, n0 = blockIdx.x * BN;
    int wave = tid >> 6, lane = tid & 63;
    int wr = wave >> 1, wc = wave & 1;  // 2x2 wave grid: 64 rows x 32 cols per wave
    int lrow = lane & 15, quad = lane >> 4;

    f32x4 acc[4][2];
#pragma unroll
    for (int i = 0; i < 4; i++)
#pragma unroll
        for (int j = 0; j < 2; j++) acc[i][j] = (f32x4){0.f, 0.f, 0.f, 0.f};

    for (int k0 = 0; k0 < K; k0 += BK) {
        // ---- stage A: 8 row-tiles x 16 kb-units = 128 unit16s, 8 gll16/thread ----
#pragma unroll
        for (int j = 0; j < 8; j++) {
            int fi = j * 256 + tid;
            int u = fi >> 4, l = fi & 15;
            int tile = u >> 4, kb = u & 15;
            int gr = min(m0 + tile * 16 + l, M - 1);  // clamp: OOB rows unused in epilogue
            gll16(A + (size_t)gr * K + k0 + kb * 8, &As[(fi & ~63) * 8]);
        }
        // ---- stage B: 4 n-tiles x 16 kb-units = 64 unit16s, 4 gll16/thread ----
#pragma unroll
        for (int j = 0; j < 4; j++) {
            int fi = j * 256 + tid;
            int u = fi >> 4, l = fi & 15;
            int tile = u >> 4, kb = u & 15;
            gll16(Bt + (size_t)(n0 + tile * 16 + l) * K + k0 + kb * 8, &Bs[(fi & ~63) * 8]);
        }
        __syncthreads();
#pragma unroll
        for (int s = 0; s < 4; s++) {
            short8 af[4], bf[2];
#pragma unroll
            for (int mt = 0; mt < 4; mt++)
                af[mt] = *(const short8*)&As[(((wr * 4 + mt) * 16 + s * 4 + quad) * 16 + lrow) * 8];
#pragma unroll
            for (int nt = 0; nt < 2; nt++)
                bf[nt] = *(const short8*)&Bs[(((wc * 2 + nt) * 16 + s * 4 + quad) * 16 + lrow) * 8];
#pragma unroll
            for (int mt = 0; mt < 4; mt++)
#pragma unroll
                for (int nt = 0; nt < 2; nt++)
                    acc[mt][nt] = __builtin_amdgcn_mfma_f32_16x16x32_bf16(af[mt], bf[nt],
                                                                         acc[mt][nt], 0, 0, 0);
        }
        __syncthreads();
    }

    // ---- epilogue ----
#pragma unroll
    for (int nt = 0; nt < 2; nt++) {
        int gc = n0 + wc * 32 + nt * 16 + lrow;
        float bs = bias2 ? ((gc < 128) ? bias[gc] : bias2[gc - 128]) : bias[gc];
        float g = 0.f, bb = 0.f, mm = 0.f, inv = 0.f;
        if (mode >= 1) {
            g = g_[gc];
            bb = b_[gc];
            mm = m_[gc];
            inv = rsqrtf(v_[gc] + 1e-5f);
        }
#pragma unroll
        for (int mt = 0; mt < 4; mt++) {
#pragma unroll
            for (int r = 0; r < 4; r++) {
                int gr = m0 + wr * 64 + mt * 16 + quad * 4 + r;
                if (gr < M) {
                    float v = acc[mt][nt][r] + bs;
                    size_t idx = (size_t)gr * N + gc;
                    if (mode == 0) {
                        OutB[idx] = f2bf(v);
                    } else if (mode == 1) {
                        OutB[idx] = f2bf(fmaxf(g * (v - mm) * inv + bb, 0.f));
                    } else {
                        float h = v + ((mode >= 3) ? bf2f(HB[idx]) : 0.f);
                        if (mode <= 3) HB[idx] = f2bf(h);
                        OutB[idx] = f2bf(fmaxf(g * (h - mm) * inv + bb, 0.f));
                    }
                }
            }
        }
    }
}

// ---------------- Fused GENConv aggregation ----------------
// ONE wave per dst node; each lane owns TWO features (ushort2 gather: one address
// chain + one load serves 2 feats). 4 independent waves per 256-block. No-max
// softmax (shift-invariant; z = msg*t bounded, exp cannot overflow).

__global__ __launch_bounds__(256) void agg_kernel(
    const unsigned short* __restrict__ xs, int xss,
    const unsigned short* __restrict__ xd, int xds,
    const int2* __restrict__ sedge, const int* __restrict__ off,
    const float* __restrict__ ew, const float* __restrict__ eb,
    const float* __restrict__ tptr, unsigned short* __restrict__ outb) {
    int wave = threadIdx.x >> 6, lane = threadIdx.x & 63;
    int d = blockIdx.x * 4 + wave;
    if (d >= Nn) return;
    int s0 = off[d], s1 = off[d + 1];
    float2 wv = *(const float2*)(ew + lane * 2);
    float2 bv = *(const float2*)(eb + lane * 2);
    float tl = tptr[0];
    float den0 = 0.f, num0 = 0.f, den1 = 0.f, num1 = 0.f;

#define EDGE_STEP(u, av)                                                        \
    {                                                                           \
        float x0 = __uint_as_float((u) << 16);                                  \
        float x1 = __uint_as_float((u)&0xFFFF0000u);                            \
        float m0v = fmaxf(x0 + fmaf((av), wv.x, bv.x), 0.f) + 1e-7f;            \
        float m1v = fmaxf(x1 + fmaf((av), wv.y, bv.y), 0.f) + 1e-7f;            \
        float e0 = __expf(m0v * tl);                                            \
        float e1 = __expf(m1v * tl);                                            \
        den0 += e0; num0 = fmaf(m0v, e0, num0);                                 \
        den1 += e1; num1 = fmaf(m1v, e1, num1);                                 \
    }

    int j = s0;
    for (; j + 3 < s1; j += 4) {
        int2 e0 = sedge[j], e1 = sedge[j + 1], e2 = sedge[j + 2], e3 = sedge[j + 3];
        unsigned int u0 = *(const unsigned int*)(xs + (size_t)e0.x * xss + lane * 2);
        unsigned int u1 = *(const unsigned int*)(xs + (size_t)e1.x * xss + lane * 2);
        unsigned int u2 = *(const unsigned int*)(xs + (size_t)e2.x * xss + lane * 2);
        unsigned int u3 = *(const unsigned int*)(xs + (size_t)e3.x * xss + lane * 2);
        EDGE_STEP(u0, __int_as_float(e0.y))
        EDGE_STEP(u1, __int_as_float(e1.y))
        EDGE_STEP(u2, __int_as_float(e2.y))
        EDGE_STEP(u3, __int_as_float(e3.y))
    }
    for (; j < s1; j++) {
        int2 e = sedge[j];
        unsigned int u = *(const unsigned int*)(xs + (size_t)e.x * xss + lane * 2);
        EDGE_STEP(u, __int_as_float(e.y))
    }
    float agg0 = num0 / fmaxf(den0, 1e-16f);  // empty segment -> 0, matches ref
    float agg1 = num1 / fmaxf(den1, 1e-16f);
    unsigned int xu = *(const unsigned int*)(xd + (size_t)d * xds + lane * 2);
    float o0 = agg0 + __uint_as_float(xu << 16);
    float o1 = agg1 + __uint_as_float(xu & 0xFFFF0000u);
    unsigned int packed = (unsigned int)f2bf(o0) | ((unsigned int)f2bf(o1) << 16);
    *(unsigned int*)(outb + (size_t)d * Hh + lane * 2) = packed;
#undef EDGE_STEP
}

// ---------------- mean-pool over pre-normed bf16 ----------------

#define PCHUNK 100

__global__ __launch_bounds__(128) void pool_kernel(
    const unsigned short* __restrict__ hb, const int* __restrict__ batch,
    float* __restrict__ pooled, float* __restrict__ cnt) {
    int hh = threadIdx.x;
    int i0 = blockIdx.x * PCHUNK;
    int i1 = min(i0 + PCHUNK, Nn);
    if (i0 >= Nn) return;
    int cur = batch[i0];
    float sum = 0.f, c = 0.f;
    for (int i = i0; i < i1; i++) {
        int gid = batch[i];
        float val = bf2f(hb[(size_t)i * Hh + hh]);
        if (gid != cur) {
            atomicAdd(&pooled[(size_t)cur * Hh + hh], sum);
            if (hh == 0) atomicAdd(&cnt[cur], c);
            cur = gid;
            sum = 0.f;
            c = 0.f;
        }
        sum += val;
        c += 1.f;
    }
    atomicAdd(&pooled[(size_t)cur * Hh + hh], sum);
    if (hh == 0) atomicAdd(&cnt[cur], c);
}

// ---------------- classifier ----------------

__global__ __launch_bounds__(128) void cls_kernel(const float* __restrict__ pooled,
                                                  const float* __restrict__ cnt,
                                                  const float* __restrict__ clinical,
                                                  const float* __restrict__ w,
                                                  const float* __restrict__ bias,
                                                  float* __restrict__ out) {
    int t = threadIdx.x;
    int g = t >> 1, c = t & 1;
    float inv = 1.f / fmaxf(cnt[g], 1.f);
    float s = bias[c];
    for (int j = 0; j < Hh; j++) s += pooled[g * Hh + j] * inv * w[j * NCc + c];
    for (int k = 0; k < Kk; k++) s += clinical[g * Kk + k] * w[(Hh + k) * NCc + c];
    out[g * NCc + c] = s;
}

// ---------------- launch ----------------

extern "C" void kernel_launch(void* const* d_in, const int* in_sizes, int n_in,
                              void* d_out, int out_size, void* d_ws, size_t ws_size,
                              hipStream_t stream) {
    const float* x = (const float*)d_in[0];
    const int* eidx = (const int*)d_in[1];
    const float* eattr = (const float*)d_in[2];
    const int* batch = (const int*)d_in[3];
    const float* clinical = (const float*)d_in[4];
    const float* lin_src_b = (const float*)d_in[6];
    const float* lin_dst_b = (const float*)d_in[8];
    const float* edge_w = (const float*)d_in[9];
    const float* edge_b = (const float*)d_in[10];
    const float* tt = (const float*)d_in[11];
    const float* mlp_b1 = (const float*)d_in[13];
    const float* bn_g = (const float*)d_in[14];
    const float* bn_b = (const float*)d_in[15];
    const float* bn_m = (const float*)d_in[16];
    const float* bn_v = (const float*)d_in[17];
    const float* mlp_b2 = (const float*)d_in[19];
    const float* norm_g = (const float*)d_in[20];
    const float* norm_b = (const float*)d_in[21];
    const float* norm_m = (const float*)d_in[22];
    const float* norm_v = (const float*)d_in[23];
    const float* cls_w = (const float*)d_in[24];
    const float* cls_b = (const float*)d_in[25];
    float* out = (float*)d_out;

    const int* src = eidx;
    const int* dst = eidx + Ee;

    char* ws = (char*)d_ws;
    size_t off_b = 0;
    auto alloc = [&](size_t bytes) -> void* {
        void* p = ws + off_b;
        off_b += (bytes + 255) & ~(size_t)255;
        return p;
    };
    unsigned short* xbf = (unsigned short*)alloc((size_t)Nn * Cc * 2);
    unsigned short* xsd = (unsigned short*)alloc((size_t)Nn * 256 * 2);
    unsigned short* rbuf = (unsigned short*)alloc((size_t)Nn * Hh * 2);
    unsigned short* aggout = (unsigned short*)alloc((size_t)Nn * Hh * 2);
    unsigned short* hmid = (unsigned short*)alloc((size_t)Nn * 2 * Hh * 2);
    unsigned short* pnorm = (unsigned short*)alloc((size_t)Nn * Hh * 2);
    unsigned short* hbuf = (unsigned short*)alloc((size_t)Nn * Hh * 2);
    int* deg = (int*)alloc((Nn + 1) * 4);
    int* offp = (int*)alloc((Nn + 1) * 4);
    int* pos = (int*)alloc((size_t)Nn * 4);
    int* bsum = (int*)alloc(NB * 4);
    int* boff = (int*)alloc(NB * 4);
    int2* sedge = (int2*)alloc((size_t)Ee * 8);
    float* pooled = (float*)alloc((size_t)Gg * Hh * 4);
    float* cntb = (float*)alloc(Gg * 4);
    unsigned short* wt = (unsigned short*)alloc((size_t)327680 * 2);

    hipMemsetAsync(deg, 0, (Nn + 1) * 4, stream);
    hipMemsetAsync(pooled, 0, (size_t)Gg * Hh * 4, stream);
    hipMemsetAsync(cntb, 0, Gg * 4, stream);

    hist_kernel<<<(Ee + 255) / 256, 256, 0, stream>>>(dst, deg);
    bsum_kernel<<<NB, 256, 0, stream>>>(deg, bsum);
    bscan_kernel<<<1, 256, 0, stream>>>(bsum, boff, offp);
    offsets_kernel<<<NB, 256, 0, stream>>>(deg, boff, offp, pos);
    scatter_kernel<<<(Ee + 255) / 256, 256, 0, stream>>>(src, dst, eattr, pos, sedge);
    wconv_kernel<<<1280, 256, 0, stream>>>((const float*)d_in[5], (const float*)d_in[7],
                                           (const float*)d_in[12], (const float*)d_in[18], wt);
    xconv_kernel<<<6250, 256, 0, stream>>>(x, xbf);

    const unsigned short* wt_proj = wt;
    const unsigned short* wt_w1 = wt + 65536;
    const unsigned short* wt_w2 = wt + 196608;

    // Fused projection: xsd[:, :128] = x@Wsrc+b, xsd[:, 128:] = x@Wdst+b
    gemm_kernel<<<dim3(4, GY), 256, 0, stream>>>(xbf, wt_proj, lin_src_b, lin_dst_b, nullptr,
                                                 nullptr, nullptr, nullptr, nullptr, xsd, Nn,
                                                 256, Cc, 0);

    for (int l = 0; l < Ll; l++) {
        const unsigned short* cxs;
        const unsigned short* cxd;
        int xss, xds;
        if (l == 0) {
            cxs = xsd;
            xss = 256;
            cxd = xsd + 128;
            xds = 256;
        } else {
            cxs = rbuf;
            xss = Hh;
            cxd = rbuf;
            xds = Hh;
        }
        agg_kernel<<<(Nn + 3) / 4, 256, 0, stream>>>(cxs, xss, cxd, xds, sedge, offp,
                                                     edge_w + l * Hh, edge_b + l * Hh, tt + l,
                                                     aggout);
        // w1: [N,128] @ [128,256] -> hmid (mlp-BN + ReLU, bf16); single barrier pair (K=128)
        gemm_kernel<<<dim3(4, GY), 256, 0, stream>>>(
            aggout, wt_w1 + (size_t)l * 32768, mlp_b1 + l * 2 * Hh, nullptr,
            bn_g + l * 2 * Hh, bn_b + l * 2 * Hh, bn_m + l * 2 * Hh, bn_v + l * 2 * Hh,
            nullptr, hmid, Nn, 2 * Hh, Hh, 1);
        // w2: [N,256] @ [256,128]; fused residual + next-layer (or final) norm
        int nl = (l == Ll - 1) ? 0 : (l + 1);
        int mode = (l == 0) ? 2 : ((l == Ll - 1) ? 4 : 3);
        unsigned short* outB = (l == Ll - 1) ? pnorm : rbuf;
        gemm_kernel<<<dim3(2, GY), 256, 0, stream>>>(
            hmid, wt_w2 + (size_t)l * 32768, mlp_b2 + l * Hh, nullptr,
            norm_g + nl * Hh, norm_b + nl * Hh, norm_m + nl * Hh, norm_v + nl * Hh,
            hbuf, outB, Nn, Hh, 2 * Hh, mode);
    }

    pool_kernel<<<(Nn + PCHUNK - 1) / PCHUNK, 128, 0, stream>>>(pnorm, batch, pooled, cntb);
    cls_kernel<<<1, 128, 0, stream>>>(pooled, cntb, clinical, cls_w, cls_b, out);
}